// Round 5
// baseline (1705.866 us; speedup 1.0000x reference)
//
#include <hip/hip_runtime.h>

// ---------------------------------------------------------------------------
// 3-state pair-HMM forward DP (logsumexp semiring), skewed band pipeline v2.
//   12 bands x 128 rows. One 64-lane wave per band; each lane owns TWO rows
//   (rowA = 128b+2L+1, rowB = rowA+1) and computes TWO columns per step
//   (4 cells/step): amortizes the ~126cy shfl handoff + fences over 4 cells
//   and shortens the critical path 3623 -> ~1800 steps.
//   Theta is pre-packed (separate kernel) into skew layout [b][t][lane][36]
//   so the DP loop does 9 aligned dwordx4 loads/step, prefetched 2 steps out.
//   Band handoff via global bottom rows (float4/col) + agent-scope progress.
//   Publish at block START so release's vmcnt(0) only drains stale loads.
// ---------------------------------------------------------------------------

#define MM    1536
#define NB    12
#define MP    768                 // column pairs per row
#define STEPS 832                 // 104 blocks * 8 steps >= 830 last active
#define TBLK  104
#define LOG2E 1.4426950408889634f
#define LN2   0.6931471805599453f
#define NEG2  (-1.4426950408889634e8f)   // (-1e8)*LOG2E, log2-domain -inf

#define PK_BYTES  ((size_t)NB * STEPS * 64 * 36 * 4)   // 91,963,392
#define BOT_BYTES ((size_t)NB * (MM + 1) * 4 * 4)      // 295,104

static __device__ __forceinline__ float lse3_2(float a, float b, float c) {
    float mx = fmaxf(fmaxf(a, b), c);
    float mn = fminf(fminf(a, b), c);
    float md = __builtin_amdgcn_fmed3f(a, b, c);
    return mx + __builtin_amdgcn_logf(1.0f + __builtin_amdgcn_exp2f(mn - mx)
                                           + __builtin_amdgcn_exp2f(md - mx));
}

__global__ void init_progress_kernel(int* progress) {
    if (threadIdx.x < NB) progress[threadIdx.x] = -1;
}

// packed[((b*STEPS + t)*64 + L)*36] = theta groups for (m = t-L):
//   [0..8]  th[rowA-1][2m]   (cell A1)   [9..17]  th[rowA-1][2m+1] (A2)
//   [18..26]th[rowB-1][2m]   (B1)        [27..35] th[rowB-1][2m+1] (B2)
// where rowA-1 = 128b+2L, rowB-1 = 128b+2L+1 (theta 0-indexed rows).
__global__ __launch_bounds__(64)
void pack_kernel(const float* __restrict__ theta, float* __restrict__ packed) {
    const int bt = blockIdx.x;            // b*STEPS + t
    const int b  = bt / STEPS;
    const int t  = bt - b * STEPS;
    const int L  = threadIdx.x;
    const int m  = t - L;
    float* dst = (float*)__builtin_assume_aligned(packed, 16)
                 + ((size_t)bt * 64 + L) * 36;
    if (m >= 0 && m < MP) {
        const int rA0 = b * 128 + 2 * L;
        __builtin_memcpy(dst,      theta + ((size_t)rA0 * MM + 2 * m) * 9, 72);
        __builtin_memcpy(dst + 18, theta + ((size_t)(rA0 + 1) * MM + 2 * m) * 9, 72);
    } else {
        #pragma unroll
        for (int i = 0; i < 36; ++i) dst[i] = 0.0f;
    }
}

template <bool PACKED>
__global__ __launch_bounds__(64, 1)
void hmm_fwd_kernel(const float* __restrict__ packed,
                    const float* __restrict__ theta,
                    float* __restrict__ out,
                    float* __restrict__ bottom,
                    int* __restrict__ progress)
{
    const int b = blockIdx.x;
    const int L = threadIdx.x;

    const float* __restrict__ bsrc = (const float*)__builtin_assume_aligned(
        bottom + (size_t)(b > 0 ? b - 1 : 0) * ((MM + 1) * 4), 16);
    float* __restrict__ bdst = (float*)__builtin_assume_aligned(
        bottom + (size_t)b * ((MM + 1) * 4), 16);

    float thbuf[4][36];     // theta slots, prefetch distance 2 steps
    float fbuf[4][8];       // feed slots: slot for step t holds cols 2t+3,2t+4

    // state: pd=V[rowA-1][2m], pu1=V[rowA-1][2m+1], pu2=V[rowA-1][2m+2],
    //        la=V[rowA][2m], lb=V[rowB][2m]  (all log2-domain)
    float pd0, pd1, pd2, pu10, pu11, pu12, pu20, pu21, pu22;
    float la0, la1, la2, lb0, lb1, lb2, res0, res1, res2;

    pd0 = pd1 = pd2 = (b == 0 && L == 0) ? 0.0f : NEG2;   // V[0][0] = 0
    pu10 = pu11 = pu12 = NEG2;
    pu20 = pu21 = pu22 = NEG2;
    la0 = la1 = la2 = NEG2;
    lb0 = lb1 = lb2 = NEG2;
    res0 = res1 = res2 = NEG2;

    #pragma unroll
    for (int s = 0; s < 4; ++s)
        #pragma unroll
        for (int i = 0; i < 8; ++i) fbuf[s][i] = NEG2;

    if (b > 0) {
        // pre-loop: cover prime (cols<=6) + blocks t0=0..15 (cols<=38)
        while (__hip_atomic_load(&progress[b - 1], __ATOMIC_ACQUIRE,
                                 __HIP_MEMORY_SCOPE_AGENT) < 40)
            __builtin_amdgcn_s_sleep(2);
        float tmp[8];
        __builtin_memcpy(tmp, bsrc + 4, 32);            // cols 1,2
        pu10 = (L == 0) ? tmp[0] : NEG2;
        pu11 = (L == 0) ? tmp[1] : NEG2;
        pu12 = (L == 0) ? tmp[2] : NEG2;
        pu20 = (L == 0) ? tmp[4] : NEG2;
        pu21 = (L == 0) ? tmp[5] : NEG2;
        pu22 = (L == 0) ? tmp[6] : NEG2;
        __builtin_memcpy(fbuf[0], bsrc + 3 * 4, 32);    // cols 3,4 (step 0)
        __builtin_memcpy(fbuf[1], bsrc + 5 * 4, 32);    // cols 5,6 (step 1)
    }

    auto load_slot = [&](float* dst, int tt) {
        if constexpr (PACKED) {
            __builtin_memcpy(dst,
                (const float*)__builtin_assume_aligned(packed, 16)
                    + ((size_t)(b * STEPS + tt) * 64 + L) * 36, 144);
        } else {
            int mc = tt - L; mc = mc < 0 ? 0 : (mc > MP - 1 ? MP - 1 : mc);
            const int rA0 = b * 128 + 2 * L;
            __builtin_memcpy(dst,      theta + ((size_t)rA0 * MM + 2 * mc) * 9, 72);
            __builtin_memcpy(dst + 18, theta + ((size_t)(rA0 + 1) * MM + 2 * mc) * 9, 72);
        }
    };
    load_slot(thbuf[0], 0);
    load_slot(thbuf[1], 1);

    for (int tb = 0; tb < TBLK; ++tb) {
        const int t0 = tb * 8;

        // producer publish at block START: outstanding prefetches are >=6
        // steps old, so the release's vmcnt(0) drain is cheap.
        if (b < NB - 1 && t0 >= 64 && L == 0) {
            int val = 2 * t0 - 126;                 // cols covered by t<=t0-1
            if (val > MM) val = MM;
            __hip_atomic_store(&progress[b], val, __ATOMIC_RELEASE,
                               __HIP_MEMORY_SCOPE_AGENT);
        }
        // consumer poll every 16 steps: covers feed accesses through col
        // 2*(t0+15)+8 = 2*t0+38
        if (b > 0 && t0 > 0 && (t0 & 15) == 0) {
            int need = 2 * t0 + 38; if (need > MM) need = MM;
            while (__hip_atomic_load(&progress[b - 1], __ATOMIC_ACQUIRE,
                                     __HIP_MEMORY_SCOPE_AGENT) < need)
                __builtin_amdgcn_s_sleep(2);
        }

        #pragma unroll
        for (int k = 0; k < 8; ++k) {
            const int t = t0 + k;

            // prefetch distance 2
            int tp = t + 2; if (tp > STEPS - 1) tp = STEPS - 1;
            load_slot(thbuf[(k + 2) & 3], tp);
            if (b > 0) {
                int jn = 2 * t + 7; if (jn > MM - 1) jn = MM - 1;
                __builtin_memcpy(fbuf[(k + 2) & 3], bsrc + (size_t)jn * 4, 32);
            }

            const float* g = thbuf[k & 3];
            const int m = t - L;
            const bool act = (m >= 0) && (m < MP);

            float x0, x1, x2;
            // cell A1 (rowA, col 2m+1): diag=pd, up=pu1, left=la
            x0 = fmaf(g[0], LOG2E, pd0);  x1 = fmaf(g[1], LOG2E, pd1);  x2 = fmaf(g[2], LOG2E, pd2);
            float nA1_0 = lse3_2(x0, x1, x2);
            x0 = fmaf(g[3], LOG2E, pu10); x1 = fmaf(g[4], LOG2E, pu11); x2 = fmaf(g[5], LOG2E, pu12);
            float nA1_1 = lse3_2(x0, x1, x2);
            x0 = fmaf(g[6], LOG2E, la0);  x1 = fmaf(g[7], LOG2E, la1);  x2 = fmaf(g[8], LOG2E, la2);
            float nA1_2 = lse3_2(x0, x1, x2);

            // cell A2 (rowA, col 2m+2): diag=pu1, up=pu2, left=nA1
            x0 = fmaf(g[9],  LOG2E, pu10); x1 = fmaf(g[10], LOG2E, pu11); x2 = fmaf(g[11], LOG2E, pu12);
            float nA2_0 = lse3_2(x0, x1, x2);
            x0 = fmaf(g[12], LOG2E, pu20); x1 = fmaf(g[13], LOG2E, pu21); x2 = fmaf(g[14], LOG2E, pu22);
            float nA2_1 = lse3_2(x0, x1, x2);
            x0 = fmaf(g[15], LOG2E, nA1_0); x1 = fmaf(g[16], LOG2E, nA1_1); x2 = fmaf(g[17], LOG2E, nA1_2);
            float nA2_2 = lse3_2(x0, x1, x2);

            // cell B1 (rowB, col 2m+1): diag=la, up=nA1, left=lb
            x0 = fmaf(g[18], LOG2E, la0);  x1 = fmaf(g[19], LOG2E, la1);  x2 = fmaf(g[20], LOG2E, la2);
            float nB1_0 = lse3_2(x0, x1, x2);
            x0 = fmaf(g[21], LOG2E, nA1_0); x1 = fmaf(g[22], LOG2E, nA1_1); x2 = fmaf(g[23], LOG2E, nA1_2);
            float nB1_1 = lse3_2(x0, x1, x2);
            x0 = fmaf(g[24], LOG2E, lb0);  x1 = fmaf(g[25], LOG2E, lb1);  x2 = fmaf(g[26], LOG2E, lb2);
            float nB1_2 = lse3_2(x0, x1, x2);

            // cell B2 (rowB, col 2m+2): diag=nA1, up=nA2, left=nB1
            x0 = fmaf(g[27], LOG2E, nA1_0); x1 = fmaf(g[28], LOG2E, nA1_1); x2 = fmaf(g[29], LOG2E, nA1_2);
            float nB2_0 = lse3_2(x0, x1, x2);
            x0 = fmaf(g[30], LOG2E, nA2_0); x1 = fmaf(g[31], LOG2E, nA2_1); x2 = fmaf(g[32], LOG2E, nA2_2);
            float nB2_1 = lse3_2(x0, x1, x2);
            x0 = fmaf(g[33], LOG2E, nB1_0); x1 = fmaf(g[34], LOG2E, nB1_1); x2 = fmaf(g[35], LOG2E, nB1_2);
            float nB2_2 = lse3_2(x0, x1, x2);

            // mask escaping values (A2 -> la, B1/B2 -> shfl/store/lb)
            nA2_0 = act ? nA2_0 : NEG2; nA2_1 = act ? nA2_1 : NEG2; nA2_2 = act ? nA2_2 : NEG2;
            nB1_0 = act ? nB1_0 : NEG2; nB1_1 = act ? nB1_1 : NEG2; nB1_2 = act ? nB1_2 : NEG2;
            nB2_0 = act ? nB2_0 : NEG2; nB2_1 = act ? nB2_1 : NEG2; nB2_2 = act ? nB2_2 : NEG2;

            // producer: lane 63's rowB is the band's bottom row (row 128(b+1))
            if (b < NB - 1 && L == 63 && act) {
                float st[8] = {nB1_0, nB1_1, nB1_2, 0.0f,
                               nB2_0, nB2_1, nB2_2, 0.0f};
                __builtin_memcpy(bdst + (size_t)(2 * m + 1) * 4, st, 32);
            }
            if (b == NB - 1) {
                const bool fin = (L == 63) && (t == 830);   // m = 767
                res0 = fin ? nB2_0 : res0;
                res1 = fin ? nB2_1 : res1;
                res2 = fin ? nB2_2 : res2;
            }

            // rotate state for step t+1
            float opu20 = pu20, opu21 = pu21, opu22 = pu22;
            float s0 = __shfl_up(nB1_0, 1, 64);
            float s1 = __shfl_up(nB1_1, 1, 64);
            float s2 = __shfl_up(nB1_2, 1, 64);
            float s3 = __shfl_up(nB2_0, 1, 64);
            float s4 = __shfl_up(nB2_1, 1, 64);
            float s5 = __shfl_up(nB2_2, 1, 64);
            const float* fb = fbuf[k & 3];       // cols 2t+3, 2t+4
            pu10 = (L == 0) ? fb[0] : s0;
            pu11 = (L == 0) ? fb[1] : s1;
            pu12 = (L == 0) ? fb[2] : s2;
            pu20 = (L == 0) ? fb[4] : s3;
            pu21 = (L == 0) ? fb[5] : s4;
            pu22 = (L == 0) ? fb[6] : s5;
            pd0 = opu20; pd1 = opu21; pd2 = opu22;
            la0 = nA2_0; la1 = nA2_1; la2 = nA2_2;
            lb0 = nB2_0; lb1 = nB2_1; lb2 = nB2_2;
        }
    }

    if (b < NB - 1) {
        if (L == 0)
            __hip_atomic_store(&progress[b], MM, __ATOMIC_RELEASE,
                               __HIP_MEMORY_SCOPE_AGENT);
    } else if (L == 63) {
        out[0] = LN2 * lse3_2(res0, res1, res2);
    }
}

extern "C" void kernel_launch(void* const* d_in, const int* in_sizes, int n_in,
                              void* d_out, int out_size, void* d_ws, size_t ws_size,
                              hipStream_t stream)
{
    const float* theta = (const float*)d_in[0];
    float* out = (float*)d_out;

    const size_t need = PK_BYTES + BOT_BYTES + 256;
    if (ws_size >= need) {
        float* packed   = (float*)d_ws;
        float* bottom   = (float*)((char*)d_ws + PK_BYTES);
        int*   progress = (int*)((char*)d_ws + PK_BYTES + BOT_BYTES);
        init_progress_kernel<<<1, 64, 0, stream>>>(progress);
        pack_kernel<<<NB * STEPS, 64, 0, stream>>>(theta, packed);
        hmm_fwd_kernel<true><<<NB, 64, 0, stream>>>(packed, theta, out,
                                                    bottom, progress);
    } else {
        float* bottom   = (float*)d_ws;
        int*   progress = (int*)((char*)d_ws + BOT_BYTES);
        init_progress_kernel<<<1, 64, 0, stream>>>(progress);
        hmm_fwd_kernel<false><<<NB, 64, 0, stream>>>(nullptr, theta, out,
                                                     bottom, progress);
    }
}